// Round 14
// baseline (194.828 us; speedup 1.0000x reference)
//
#include <hip/hip_runtime.h>

#define L  2048
#define D  64
#define NH 16
#define NB 2
#define KT 64
#define NT 32
#define LOG2E 1.44269504088896f

using half8   = _Float16 __attribute__((ext_vector_type(8)));
using half4v  = _Float16 __attribute__((ext_vector_type(4)));
using float4v = float    __attribute__((ext_vector_type(4)));
using int4v   = int      __attribute__((ext_vector_type(4)));

#define BAR()    asm volatile("s_barrier" ::: "memory")
#define WAITV(n) asm volatile("s_waitcnt vmcnt(" #n ")" ::: "memory")
#define WAITL()  asm volatile("s_waitcnt lgkmcnt(0)" ::: "memory")

__device__ __forceinline__ void gload16(const void* g, void* l) {
    __builtin_amdgcn_global_load_lds((const __attribute__((address_space(1))) void*)g,
                                     (__attribute__((address_space(3))) void*)l, 16, 0, 0);
}

// ---------------- precompute: qh = fp16(q * log2e/8), kh = fp16(k) ----------------
__global__ __launch_bounds__(256) void prep_qk(const float* __restrict__ q,
                                               const float* __restrict__ k,
                                               _Float16* __restrict__ qh,
                                               _Float16* __restrict__ kh) {
    int i = (blockIdx.x * 256 + threadIdx.x) * 8;
    float4v a0 = *(const float4v*)(q + i);
    float4v a1 = *(const float4v*)(q + i + 4);
    float4v b0 = *(const float4v*)(k + i);
    float4v b1 = *(const float4v*)(k + i + 4);
    half8 qo, ko;
    const float s = 0.125f * LOG2E;
#pragma unroll
    for (int j = 0; j < 4; ++j) {
        qo[j]     = (_Float16)(a0[j] * s);
        qo[4 + j] = (_Float16)(a1[j] * s);
        ko[j]     = (_Float16)b0[j];
        ko[4 + j] = (_Float16)b1[j];
    }
    *(half8*)(qh + i) = qo;
    *(half8*)(kh + i) = ko;
}

// ------- precompute: vt2[bh][kb(128)][d(64)][kl(16)] = fp16(v[b,h,kb*16+kl,d]) -------
__global__ __launch_bounds__(256) void prep_vt(const float* __restrict__ v,
                                               _Float16* __restrict__ vt) {
    __shared__ float tile[64][65];
    int bh = blockIdx.x >> 5;
    int l0 = (blockIdx.x & 31) * 64;
    const float* vb = v + (size_t)bh * L * D + (size_t)l0 * D;
    int row = threadIdx.x >> 2, c0 = (threadIdx.x & 3) * 16;
#pragma unroll
    for (int j = 0; j < 16; j += 4) {
        float4v t4 = *(const float4v*)(vb + row * D + c0 + j);
        tile[row][c0 + j + 0] = t4[0];
        tile[row][c0 + j + 1] = t4[1];
        tile[row][c0 + j + 2] = t4[2];
        tile[row][c0 + j + 3] = t4[3];
    }
    __syncthreads();
    int d = threadIdx.x >> 2, kbl = threadIdx.x & 3;
    int lq = kbl * 16;
    _Float16* ob = vt + (((size_t)bh * 128 + (l0 >> 4) + kbl) * 64 + d) * 16;
    half8 o0, o1;
#pragma unroll
    for (int j = 0; j < 8; ++j) {
        o0[j] = (_Float16)tile[lq + j][d];
        o1[j] = (_Float16)tile[lq + 8 + j][d];
    }
    *(half8*)(ob)     = o0;
    *(half8*)(ob + 8) = o1;
}

// ------- precompute: mbh3[b][qt32(64)][t(32)][w(4)][row(32)][kl(16)] -------
// Each wave's 32x16 M subtile = one contiguous 1KB block (single gload16).
__global__ __launch_bounds__(256) void prep_mbh(const int* __restrict__ mask,
                                                const float* __restrict__ bias,
                                                _Float16* __restrict__ mbh) {
    int blk = blockIdx.x;                   // 2048
    int bq = blk >> 4, tg = blk & 15;
    int b  = bq >> 6, qt = bq & 63;
    int row16 = threadIdx.x >> 4;           // 0..15
    int c16   = threadIdx.x & 15;           // 4-key chunk within 64-key tile
    int w = c16 >> 2, kl4 = (c16 & 3) * 4;
#pragma unroll
    for (int tt = 0; tt < 2; ++tt) {
        int t = tg * 2 + tt;
        int key = t * 64 + c16 * 4;
#pragma unroll
        for (int rr = 0; rr < 2; ++rr) {
            int row = row16 + rr * 16;
            const int*   mrow = mask + ((size_t)b * L + qt * 32 + row) * L;
            const float* brow = bias + ((size_t)b * L + qt * 32 + row) * L;
            int4v   m  = *(const int4v*)(mrow + key);
            float4v bb = *(const float4v*)(brow + key);
            half4v o;
            o[0] = m[0] ? (_Float16)(bb[0] * LOG2E) : (_Float16)(-1500.0f);
            o[1] = m[1] ? (_Float16)(bb[1] * LOG2E) : (_Float16)(-1500.0f);
            o[2] = m[2] ? (_Float16)(bb[2] * LOG2E) : (_Float16)(-1500.0f);
            o[3] = m[3] ? (_Float16)(bb[3] * LOG2E) : (_Float16)(-1500.0f);
            *(half4v*)(mbh + (size_t)bq * 65536 + t * 2048 + w * 512 + row * 16 + kl4) = o;
        }
    }
}

// ---------------- fused attention: 32 q-rows/block, K/V staged once ----------------
// Grid 2048 (b,h,qt32). 4 waves; wave w owns keys kb=t*4+w of every 64-key
// tile; per staged tile BOTH 16-row groups (A: rows 0-15, B: 16-31) are
// computed -> K/V staging traffic halves vs 16-row blocks (2.36 -> 1.33 GB).
// puhA/B = 128 VGPRs -> launch_bounds(256,2). Loop2 = 16 phases (rg x 4-tile
// groups), R13's verified t32 swizzle/store path.
__global__ __launch_bounds__(256, 2) void attn_fused(const _Float16* __restrict__ qh,
                                                     const _Float16* __restrict__ kh,
                                                     const _Float16* __restrict__ vt,
                                                     const _Float16* __restrict__ mbh,
                                                     float* __restrict__ out_ho,
                                                     float* __restrict__ out_attn) {
    // loop1: [0,16K) kbuf [w][bs][16key x 64d] | [16K,32K) vbuf [w][bs][64d x 16kl]
    //        [32K,40K) mbuf [w][bs][32row x 16kl]
    // epilogue: ored [4][32][68] f32 at [0,34.8K) | loop2: t32 dbuf [2][16][256] at [0,32K)
    __shared__ __align__(16) char arena[40960];
    __shared__ float lpart[4][32];
    __shared__ float rls[32];

    int p  = blockIdx.x;                  // XCD x: 4 heads of one b
    int l  = (p & 7) * 256 + (p >> 3);
    int b  = l >> 10, h = (l >> 6) & 15, qt = l & 63;
    int bh = b * NH + h;
    int q0 = qt * 32;

    int tid = threadIdx.x, w = tid >> 6, lane = tid & 63;
    int cg = lane & 15, grp = lane >> 4;

    const _Float16* kg = kh  + (size_t)bh * L * D;             // [l][d]
    const _Float16* vg = vt  + (size_t)bh * 131072;            // [kb][d][kl]
    const _Float16* mg = mbh + (size_t)(b * 64 + qt) * 65536;  // [t][w][row][kl]
    const _Float16* qg = qh  + ((size_t)bh * L + q0) * D;

    half8 aqA0 = *(const half8*)(qg + cg * D + grp * 8);
    half8 aqA1 = *(const half8*)(qg + cg * D + 32 + grp * 8);
    half8 aqB0 = *(const half8*)(qg + (16 + cg) * D + grp * 8);
    half8 aqB1 = *(const half8*)(qg + (16 + cg) * D + 32 + grp * 8);

    _Float16* kbw = (_Float16*)(arena)         + w * 2048;
    _Float16* vbw = (_Float16*)(arena + 16384) + w * 2048;
    _Float16* mbw = (_Float16*)(arena + 32768) + w * 1024;

    const int r8  = lane >> 3;
    const int kch = ((lane & 7) ^ r8) * 8;        // K src d-chunk, XOR-preswizzled

    auto stage = [&](int t, int bs) {
        int kb = t * 4 + w;
        int k0 = kb * 16;
        _Float16* kd = kbw + bs * 1024;
        gload16(kg + (size_t)(k0 +     r8) * D + kch, kd);
        gload16(kg + (size_t)(k0 + 8 + r8) * D + kch, kd + 512);
        _Float16* vd = vbw + bs * 1024;
        const _Float16* vs = vg + (size_t)kb * 1024;
        gload16(vs + lane * 8, vd);
        gload16(vs + 512 + lane * 8, vd + 512);
        _Float16* md = mbw + bs * 512;
        gload16(mg + (size_t)t * 2048 + w * 512 + lane * 8, md);
    };

    const int kro  = cg * 64;
    const int ks0  = ((grp)     ^ (cg & 7)) * 8;
    const int ks1  = ((4 + grp) ^ (cg & 7)) * 8;
    const int mroA = cg * 16 + grp * 4;           // M[row cg][kl grp*4..]
    const int mroB = mroA + 256;                  // M[row 16+cg][...]
    const int vro  = grp * 4;

    half4v puhA[NT], puhB[NT];                    // unnormalized e * 2^-5 (128 VGPRs)
    float lsA = 0.f, lsB = 0.f;
    float4v oaA0 = {0,0,0,0}, oaA1 = {0,0,0,0}, oaA2 = {0,0,0,0}, oaA3 = {0,0,0,0};
    float4v oaB0 = {0,0,0,0}, oaB1 = {0,0,0,0}, oaB2 = {0,0,0,0}, oaB3 = {0,0,0,0};

    // ---------------- loop 1: barrier-free QK + PV, both row-groups ----------------
    stage(0, 0);
#pragma unroll
    for (int t = 0; t < NT; ++t) {
        const int bs = t & 1;
        if (t + 1 < NT) { stage(t + 1, bs ^ 1); WAITV(5); }
        else            { WAITV(0); }
        const _Float16* kb = kbw + bs * 1024;
        const _Float16* mb = mbw + bs * 512;
        const _Float16* vb = vbw + bs * 1024;
        half8  bk0 = *(const half8*)(kb + kro + ks0);
        half8  bk1 = *(const half8*)(kb + kro + ks1);
        half4v m4A = *(const half4v*)(mb + mroA);
        half4v m4B = *(const half4v*)(mb + mroB);
        float4v accA, accB;
        accA[0] = (float)m4A[0]; accA[1] = (float)m4A[1];
        accA[2] = (float)m4A[2]; accA[3] = (float)m4A[3];
        accB[0] = (float)m4B[0]; accB[1] = (float)m4B[1];
        accB[2] = (float)m4B[2]; accB[3] = (float)m4B[3];
        __builtin_amdgcn_s_setprio(1);
        accA = __builtin_amdgcn_mfma_f32_16x16x32_f16(bk0, aqA0, accA, 0, 0, 0);
        accA = __builtin_amdgcn_mfma_f32_16x16x32_f16(bk1, aqA1, accA, 0, 0, 0);
        accB = __builtin_amdgcn_mfma_f32_16x16x32_f16(bk0, aqB0, accB, 0, 0, 0);
        accB = __builtin_amdgcn_mfma_f32_16x16x32_f16(bk1, aqB1, accB, 0, 0, 0);
        __builtin_amdgcn_s_setprio(0);
        float eA0 = exp2f(accA[0]), eA1 = exp2f(accA[1]);
        float eA2 = exp2f(accA[2]), eA3 = exp2f(accA[3]);
        float eB0 = exp2f(accB[0]), eB1 = exp2f(accB[1]);
        float eB2 = exp2f(accB[2]), eB3 = exp2f(accB[3]);
        lsA += (eA0 + eA1) + (eA2 + eA3);
        lsB += (eB0 + eB1) + (eB2 + eB3);
        half4v phA, phB;
        phA[0] = (_Float16)(eA0 * 0.03125f); phA[1] = (_Float16)(eA1 * 0.03125f);
        phA[2] = (_Float16)(eA2 * 0.03125f); phA[3] = (_Float16)(eA3 * 0.03125f);
        phB[0] = (_Float16)(eB0 * 0.03125f); phB[1] = (_Float16)(eB1 * 0.03125f);
        phB[2] = (_Float16)(eB2 * 0.03125f); phB[3] = (_Float16)(eB3 * 0.03125f);
        puhA[t] = phA;
        puhB[t] = phB;
        half4v pv0 = *(const half4v*)(vb + (cg +  0) * 16 + vro);
        half4v pv1 = *(const half4v*)(vb + (cg + 16) * 16 + vro);
        half4v pv2 = *(const half4v*)(vb + (cg + 32) * 16 + vro);
        half4v pv3 = *(const half4v*)(vb + (cg + 48) * 16 + vro);
        __builtin_amdgcn_s_setprio(1);
        oaA0 = __builtin_amdgcn_mfma_f32_16x16x16f16(phA, pv0, oaA0, 0, 0, 0);
        oaA1 = __builtin_amdgcn_mfma_f32_16x16x16f16(phA, pv1, oaA1, 0, 0, 0);
        oaA2 = __builtin_amdgcn_mfma_f32_16x16x16f16(phA, pv2, oaA2, 0, 0, 0);
        oaA3 = __builtin_amdgcn_mfma_f32_16x16x16f16(phA, pv3, oaA3, 0, 0, 0);
        oaB0 = __builtin_amdgcn_mfma_f32_16x16x16f16(phB, pv0, oaB0, 0, 0, 0);
        oaB1 = __builtin_amdgcn_mfma_f32_16x16x16f16(phB, pv1, oaB1, 0, 0, 0);
        oaB2 = __builtin_amdgcn_mfma_f32_16x16x16f16(phB, pv2, oaB2, 0, 0, 0);
        oaB3 = __builtin_amdgcn_mfma_f32_16x16x16f16(phB, pv3, oaB3, 0, 0, 0);
        __builtin_amdgcn_s_setprio(0);
    }

    // ---------------- l reduce ----------------
    lsA += __shfl_xor(lsA, 16);
    lsA += __shfl_xor(lsA, 32);
    lsB += __shfl_xor(lsB, 16);
    lsB += __shfl_xor(lsB, 32);
    if (grp == 0) { lpart[w][cg] = lsA; lpart[w][16 + cg] = lsB; }
    __syncthreads();                       // also closes loop-1 LDS use
    float ltA = (lpart[0][cg] + lpart[1][cg]) + (lpart[2][cg] + lpart[3][cg]);
    float ltB = (lpart[0][16 + cg] + lpart[1][16 + cg]) + (lpart[2][16 + cg] + lpart[3][16 + cg]);
    float rlA = 32.0f / ltA;               // folds the 2^-5 e-scale
    float rlB = 32.0f / ltB;
    if (w == 0 && grp == 0) { rls[cg] = rlA; rls[16 + cg] = rlB; }

    // ---------------- O reduce across waves + ho store ----------------
    float* ored = (float*)arena;           // [4][32][68], aliases staging bufs
    float* orw  = ored + w * 2176;
#pragma unroll
    for (int r = 0; r < 4; ++r) {
        orw[(grp * 4 + r) * 68 +  0 + cg] = oaA0[r];
        orw[(grp * 4 + r) * 68 + 16 + cg] = oaA1[r];
        orw[(grp * 4 + r) * 68 + 32 + cg] = oaA2[r];
        orw[(grp * 4 + r) * 68 + 48 + cg] = oaA3[r];
        orw[(16 + grp * 4 + r) * 68 +  0 + cg] = oaB0[r];
        orw[(16 + grp * 4 + r) * 68 + 16 + cg] = oaB1[r];
        orw[(16 + grp * 4 + r) * 68 + 32 + cg] = oaB2[r];
        orw[(16 + grp * 4 + r) * 68 + 48 + cg] = oaB3[r];
    }
    __syncthreads();
    {
        int qr = tid >> 3, d8 = (tid & 7) * 8;     // 32 rows x 8 floats
        float rlo = rls[qr];
        float4v u0 = {0,0,0,0}, u1 = {0,0,0,0};
#pragma unroll
        for (int ww = 0; ww < 4; ++ww) {
            float4v a = *(const float4v*)(ored + ww * 2176 + qr * 68 + d8);
            float4v c = *(const float4v*)(ored + ww * 2176 + qr * 68 + d8 + 4);
            u0[0] += a[0]; u0[1] += a[1]; u0[2] += a[2]; u0[3] += a[3];
            u1[0] += c[0]; u1[1] += c[1]; u1[2] += c[2]; u1[3] += c[3];
        }
        u0[0] *= rlo; u0[1] *= rlo; u0[2] *= rlo; u0[3] *= rlo;
        u1[0] *= rlo; u1[1] *= rlo; u1[2] *= rlo; u1[3] *= rlo;
        float* ob = out_ho + ((size_t)bh * L + q0 + qr) * D + d8;
        __builtin_nontemporal_store(u0, (float4v*)(ob));
        __builtin_nontemporal_store(u1, (float4v*)(ob + 4));
    }
    __syncthreads();                       // ored readers done before t32 overwrites

    // ---------------- loop 2: attn stores, 16 phases (rg x 4-tile groups) ----------------
    float* arow0 = out_attn + ((size_t)bh * L + q0) * L;
    float* t32f  = (float*)arena;                  // dbuf [2][16][256] f32
    const int gbase = w * 4 + grp;
    const int swrow = tid >> 4, jj = tid & 15;

#pragma unroll
    for (int ph = 0; ph < 16; ++ph) {
        const int rg = ph & 1, tg = ph >> 1;
        float* tb = t32f + (ph & 1) * 4096;
        const float rr = (rg == 0) ? rlA : rlB;
#pragma unroll
        for (int i = 0; i < 4; ++i) {
            const int tt = tg * 4 + i;
            const half4v ph4 = (rg == 0) ? puhA[tt] : puhB[tt];   // static: ph,i literal
            float4v pn;
            pn[0] = (float)ph4[0] * rr; pn[1] = (float)ph4[1] * rr;
            pn[2] = (float)ph4[2] * rr; pn[3] = (float)ph4[3] * rr;
            int g = (i * 16 + gbase) ^ (cg & 7);
            *(float4v*)(tb + cg * 256 + g * 4) = pn;
        }
        WAITL();
        BAR();
        float* arow = arow0 + (size_t)(rg * 16) * L;
#pragma unroll
        for (int k = 0; k < 4; ++k) {
            int g = (jj + 16 * k) ^ (swrow & 7);
            float4v s = *(const float4v*)(tb + swrow * 256 + g * 4);
            __builtin_nontemporal_store(s,
                (float4v*)(arow + (size_t)swrow * L + tg * 256 + (jj + 16 * k) * 4));
        }
    }
}

extern "C" void kernel_launch(void* const* d_in, const int* in_sizes, int n_in,
                              void* d_out, int out_size, void* d_ws, size_t ws_size,
                              hipStream_t stream) {
    const float* q    = (const float*)d_in[0];
    const float* k    = (const float*)d_in[1];
    const float* v    = (const float*)d_in[2];
    const int*   mask = (const int*)d_in[3];
    const float* bias = (const float*)d_in[4];

    float* ho   = (float*)d_out;
    float* attn = (float*)d_out + (size_t)NB * NH * L * D;

    char* ws = (char*)d_ws;
    _Float16* qh  = (_Float16*)(ws);                       //  8 MB
    _Float16* kh  = (_Float16*)(ws + ((size_t)8  << 20));  //  8 MB
    _Float16* vt  = (_Float16*)(ws + ((size_t)16 << 20));  //  8 MB (tiled)
    _Float16* mbh = (_Float16*)(ws + ((size_t)24 << 20));  // 16.8 MB (tiled, 32-row)
    (void)in_sizes; (void)n_in; (void)out_size; (void)ws_size;

    prep_qk<<<2048, 256, 0, stream>>>(q, k, qh, kh);
    prep_vt<<<1024, 256, 0, stream>>>(v, vt);
    prep_mbh<<<2048, 256, 0, stream>>>(mask, bias, mbh);
    attn_fused<<<2048, 256, 0, stream>>>(qh, kh, vt, mbh, ho, attn);
}